// Round 9
// baseline (1500.077 us; speedup 1.0000x reference)
//
#include <hip/hip_runtime.h>

typedef unsigned short u16;
typedef unsigned int u32;

#define BZ 16
#define CIN 3
#define C 64
#define N_ 307
#define T_ 24
#define BT (BZ*T_)          // 384
#define ROWS (BT*N_)        // 117888
#define CNT (C*N_*T_)       // 471552

#define OUT_ELEMS 7544832
#define S_ELEMS   36191616

__device__ __forceinline__ float bf(const u16* p, int i) {
    union { unsigned u; float f; } x; x.u = ((unsigned)p[i]) << 16; return x.f;
}
__device__ __forceinline__ u16 f2b(float v) {
    union { float f; unsigned u; } x; x.f = v;
    unsigned u = x.u;
    unsigned rb = (u >> 16) & 1u;
    u += 0x7fffu + rb;
    return (u16)(u >> 16);
}
__device__ __forceinline__ float wave_sum(float v) {
#pragma unroll
    for (int m = 32; m > 0; m >>= 1) v += __shfl_xor(v, m);
    return v;
}
__device__ __forceinline__ float rdlane(float v, int l) {
    return __int_as_float(__builtin_amdgcn_readlane(__float_as_int(v), l));
}

// temporal conv (lrelu 0.01) for 4 rows owned by this wave; lane = out channel
__device__ __forceinline__ void tconv4(const float* __restrict__ x,
        const float* __restrict__ tmw, const float* __restrict__ tmb,
        int b, int t, int n0, int lane, float xt4[4])
{
#pragma unroll
    for (int r = 0; r < 4; ++r) {
        int n = n0 + r;
        float acc = tmb[lane];
        if (n < N_) {
#pragma unroll
            for (int ci = 0; ci < CIN; ++ci) {
                const float* xp = x + ((b*CIN + ci)*N_ + n)*T_;
                float wa = tmw[(lane*CIN + ci)*3 + 0];
                float wb = tmw[(lane*CIN + ci)*3 + 1];
                float wc = tmw[(lane*CIN + ci)*3 + 2];
                if (t > 0)      acc += wa * xp[t - 1];
                acc += wb * xp[t];
                if (t < T_ - 1) acc += wc * xp[t + 1];
            }
        }
        xt4[r] = acc > 0.f ? acc : 0.01f * acc;
    }
}

// GAT weight: w = adj ? exp(lrelu_0.3(hs+hd)) : 0 (no max-subtract: identical
// softmax; e ~ N(0,0.3) so expf cannot overflow; masked entries exact 0)
__device__ __forceinline__ float gatw(const float* __restrict__ sup,
        int n, int m, bool mv, float hsv, float hdv)
{
    float wv = 0.f;
    if (mv && n < N_) {
        bool adj = sup[n*N_ + m] > 0.f;
        float ea = hsv + hdv; ea = ea > 0.f ? ea : 0.3f*ea;
        wv = adj ? expf(ea) : 0.f;
    }
    return wv;
}

// ===== kGAT<G>: temporal conv + single GAT (h GEMM, softmax, att@h) ==========
// Grid (2, BT): blockIdx.x = row-half (rows [half*160, half*160+160)),
// blockIdx.y = (b,t). 256 threads = 4 waves. Phase 1 (full h, cheap) is
// duplicated per half; phase 2 (dominant) splits. 768 blocks = 3/CU exact
// (round-8 post-mortem: 384x512 @60KB LDS = 2/CU max -> half the CUs hosted
// 2 blocks, half 1 -> ~33% imbalance waste at 29% occupancy).
// W lives in registers (dead after phase 1) so LDS ~43KB -> 3 blocks/CU.
template<int G>
__global__ __launch_bounds__(256) void kGAT(
        const float* __restrict__ x, const float* __restrict__ sup,
        const float* __restrict__ tmw, const float* __restrict__ tmb,
        const float* __restrict__ W, const float* __restrict__ asp,
        const float* __restrict__ adp,
        const float* __restrict__ t1w, const float* __restrict__ t2w,
        float* __restrict__ agbuf, float* __restrict__ f1,
        float* __restrict__ f2part)
{
    __shared__ u16 sH[N_*64];        // 38.4 KB (bf16 h)
    __shared__ float sHs[320];
    __shared__ float sHd[320];
    __shared__ float sF2[4*64];      // 1 KB

    int half = blockIdx.x;
    int bt = blockIdx.y;
    int b = bt / T_, t = bt - b * T_;
    int tid = threadIdx.x;
    int w = tid >> 6, lane = tid & 63;

    // W column for this lane in registers
    float wreg[64];
#pragma unroll
    for (int c = 0; c < 64; ++c) wreg[c] = W[c*64 + lane];

    float asv = asp[lane], adv = adp[lane];

    // ---- phase 1: full h = xt@W + hs/hd projections (all 307 rows) ----
#pragma unroll 1
    for (int g = 0; g < 20; ++g) {
        int n0 = g * 16 + w * 4;
        float xt4[4];
        tconv4(x, tmw, tmb, b, t, n0, lane, xt4);
        float h[4] = {0,0,0,0};
#pragma unroll
        for (int c = 0; c < 64; ++c) {
#pragma unroll
            for (int r = 0; r < 4; ++r) h[r] += rdlane(xt4[r], c) * wreg[c];
        }
#pragma unroll
        for (int r = 0; r < 4; ++r) {
            int n = n0 + r;
            float v1 = wave_sum(h[r] * asv);
            float v2 = wave_sum(h[r] * adv);
            if (n < N_) {
                sH[n*64 + lane] = f2b(h[r]);
                if (lane == 0) { sHs[n] = v1; sHd[n] = v2; }
            }
        }
    }
    __syncthreads();

    // ---- phase 2: this half's rows: softmax (2-pass recompute) + att@h ----
    float t1v = t1w[lane];
    float f2acc = 0.f;
#pragma unroll 1
    for (int g = 0; g < 10; ++g) {
        int n0 = half * 160 + g * 16 + w * 4;
        float hsv[4], sm[4], inv[4];
#pragma unroll
        for (int r = 0; r < 4; ++r) {
            int n = n0 + r;
            hsv[r] = (n < N_) ? sHs[n] : 0.f;
            sm[r] = 0.f;
        }
        // pass A: unnormalized sums
#pragma unroll 1
        for (int c5 = 0; c5 < 5; ++c5) {
            int m = c5*64 + lane;
            bool mv = m < N_;
            float hdv = mv ? sHd[m] : 0.f;
#pragma unroll
            for (int r = 0; r < 4; ++r)
                sm[r] += gatw(sup, n0 + r, m, mv, hsv[r], hdv);
        }
#pragma unroll
        for (int r = 0; r < 4; ++r) {
            float s = wave_sum(sm[r]);
            inv[r] = (s > 0.f) ? 1.f / s : 0.f;
        }
        // pass B: chunk-recompute weights + readlane att@h
        float ac[4] = {0,0,0,0};
#pragma unroll 1
        for (int c5 = 0; c5 < 5; ++c5) {
            int m = c5*64 + lane;
            bool mv = m < N_;
            float hdv = mv ? sHd[m] : 0.f;
            float w4[4];
#pragma unroll
            for (int r = 0; r < 4; ++r)
                w4[r] = gatw(sup, n0 + r, m, mv, hsv[r], hdv);
#pragma unroll
            for (int s = 0; s < 64; ++s) {
                int mm = c5*64 + s;
                if (mm < N_) {   // compile-time fold (c5<4 always; c5==4: s<51)
                    float hv = bf(sH, mm*64 + lane);
#pragma unroll
                    for (int r = 0; r < 4; ++r) ac[r] += rdlane(w4[r], s) * hv;
                }
            }
        }
#pragma unroll
        for (int r = 0; r < 4; ++r) {
            int n = n0 + r;
            size_t idx = (size_t)(bt*N_ + n)*64 + lane;
            float a = ac[r] * inv[r];
            if (G == 0) {
                if (n < N_) agbuf[idx] = a;
            } else {
                float a1 = 0.f;
                if (n < N_) a1 = agbuf[idx];
                float gt = 1.f / (1.f + expf(-a));
                float fv = a1 > 0.f ? a1 : 0.01f * a1;
                float xv = gt * fv;
                float fs = wave_sum(((n < N_) ? xv : 0.f) * t1v);
                if (n < N_) {
                    agbuf[idx] = xv;
                    if (lane == 0) f1[bt*N_ + n] = fs;
                    f2acc += xv * t2w[n];
                }
            }
        }
    }
    if (G == 1) {   // per-half f2 partial (kD sums the two halves)
        sF2[w*64 + lane] = f2acc;
        __syncthreads();
        if (tid < 64) {
            float s = 0.f;
#pragma unroll
            for (int k = 0; k < 4; ++k) s += sF2[k*64 + tid];
            f2part[(size_t)half*BZ*C*T_ + (b*C + tid)*T_ + t] = s;
        }
    }
}

// ===== kSc: recompute GAT1 softmax and write S_coef (runs LAST) ==============
__global__ __launch_bounds__(256) void kSc(
        const float* __restrict__ x, const float* __restrict__ sup,
        const float* __restrict__ tmw, const float* __restrict__ tmb,
        const float* __restrict__ W, const float* __restrict__ asp,
        const float* __restrict__ adp, float* __restrict__ Sc)
{
    __shared__ float sHs[320];
    __shared__ float sHd[320];

    int half = blockIdx.x;
    int bt = blockIdx.y;
    int b = bt / T_, t = bt - b * T_;
    int tid = threadIdx.x;
    int w = tid >> 6, lane = tid & 63;

    float wreg[64];
#pragma unroll
    for (int c = 0; c < 64; ++c) wreg[c] = W[c*64 + lane];

    float asv = asp[lane], adv = adp[lane];

#pragma unroll 1
    for (int g = 0; g < 20; ++g) {
        int n0 = g * 16 + w * 4;
        float xt4[4];
        tconv4(x, tmw, tmb, b, t, n0, lane, xt4);
        float h[4] = {0,0,0,0};
#pragma unroll
        for (int c = 0; c < 64; ++c) {
#pragma unroll
            for (int r = 0; r < 4; ++r) h[r] += rdlane(xt4[r], c) * wreg[c];
        }
#pragma unroll
        for (int r = 0; r < 4; ++r) {
            int n = n0 + r;
            float v1 = wave_sum(h[r] * asv);
            float v2 = wave_sum(h[r] * adv);
            if (n < N_ && lane == 0) { sHs[n] = v1; sHd[n] = v2; }
        }
    }
    __syncthreads();

#pragma unroll 1
    for (int g = 0; g < 10; ++g) {
        int n0 = half * 160 + g * 16 + w * 4;
        float hsv[4], sm[4], inv[4];
#pragma unroll
        for (int r = 0; r < 4; ++r) {
            int n = n0 + r;
            hsv[r] = (n < N_) ? sHs[n] : 0.f;
            sm[r] = 0.f;
        }
#pragma unroll 1
        for (int c5 = 0; c5 < 5; ++c5) {
            int m = c5*64 + lane;
            bool mv = m < N_;
            float hdv = mv ? sHd[m] : 0.f;
#pragma unroll
            for (int r = 0; r < 4; ++r)
                sm[r] += gatw(sup, n0 + r, m, mv, hsv[r], hdv);
        }
#pragma unroll
        for (int r = 0; r < 4; ++r) {
            float s = wave_sum(sm[r]);
            inv[r] = (s > 0.f) ? 1.f / s : 0.f;
        }
#pragma unroll 1
        for (int c5 = 0; c5 < 5; ++c5) {
            int m = c5*64 + lane;
            bool mv = m < N_;
            float hdv = mv ? sHd[m] : 0.f;
#pragma unroll
            for (int r = 0; r < 4; ++r) {
                int n = n0 + r;
                if (mv && n < N_)
                    Sc[(size_t)(bt*N_ + n)*N_ + m] =
                        gatw(sup, n, m, mv, hsv[r], hdv) * inv[r];
            }
        }
    }
}

// ---------------- kD0: g1[bt][c] = sum_n f1[bt][n] * tw[n][c] ----------------
__global__ __launch_bounds__(256) void kD0(const float* __restrict__ f1,
        const float* __restrict__ tw, float* __restrict__ g1)
{
    __shared__ float part[4][64];
    int bt = blockIdx.x;
    int w = threadIdx.x >> 6, lane = threadIdx.x & 63;
    float acc = 0.f;
    for (int n = w*77; n < (w+1)*77 && n < N_; ++n)
        acc += f1[bt*N_ + n] * tw[n*64 + lane];
    part[w][lane] = acc;
    __syncthreads();
    if (threadIdx.x < 64) {
        float s = part[0][threadIdx.x] + part[1][threadIdx.x]
                + part[2][threadIdx.x] + part[3][threadIdx.x];
        g1[bt*64 + threadIdx.x] = s;
    }
}

// ---------------- kD: temporal attention TATT_1 ------------------------------
__global__ __launch_bounds__(256) void kD(const float* __restrict__ g1,
        const float* __restrict__ f2part, const float* __restrict__ tb,
        const float* __restrict__ tv,
        const float* __restrict__ bng, const float* __restrict__ bnb,
        float* __restrict__ coefs, float* __restrict__ Tc,
        float* __restrict__ stats)
{
    __shared__ float g1s[T_][C];
    __shared__ float f2s[C][T_];
    __shared__ float lg[T_][T_];
    __shared__ float l2[T_][T_];
    int b = blockIdx.x, tid = threadIdx.x;
    if (tid == 0) { stats[2*b] = 0.f; stats[2*b + 1] = 0.f; }
    for (int idx = tid; idx < T_*C; idx += 256) {
        int t = idx / C, c = idx - t*C;
        g1s[t][c] = g1[(b*T_ + t)*C + c];
        int c2 = idx / T_, t2 = idx - c2*T_;
        f2s[c2][t2] = f2part[(b*C + c2)*T_ + t2]
                    + f2part[(size_t)BZ*C*T_ + (b*C + c2)*T_ + t2];
    }
    __syncthreads();
    for (int idx = tid; idx < T_*T_; idx += 256) {
        int t = idx / T_, q = idx - t*T_;
        float s = 0.f;
#pragma unroll
        for (int c = 0; c < C; ++c) s += g1s[t][c] * f2s[c][q];
        s += tb[t*T_ + q];
        lg[t][q] = 1.f / (1.f + expf(-s));
    }
    __syncthreads();
    const float bnscale = 0.99999500003749972f;  // 1/sqrt(1+1e-5)
    for (int idx = tid; idx < T_*T_; idx += 256) {
        int p = idx / T_, q = idx - p*T_;
        float s = 0.f;
#pragma unroll
        for (int t = 0; t < T_; ++t) s += tv[p*T_ + t] * lg[t][q];
        s = s * bnscale * bng[q] + bnb[q];
        if (q > p) s += -1e13f;   // causal mask
        l2[p][q] = s;
    }
    __syncthreads();
    if (tid < T_) {
        int p = tid;
        float mx = -3e38f;
#pragma unroll
        for (int q = 0; q < T_; ++q) mx = fmaxf(mx, l2[p][q]);
        float e[T_]; float sum = 0.f;
#pragma unroll
        for (int q = 0; q < T_; ++q) { e[q] = expf(l2[p][q] - mx); sum += e[q]; }
        float inv = 1.f / sum;
#pragma unroll
        for (int q = 0; q < T_; ++q) {
            float v = e[q] * inv;
            coefs[(b*T_ + p)*T_ + q] = v;
            Tc[(b*T_ + q)*T_ + p] = v;
        }
    }
}

// ---------------- kE: temporal mix + residual + LayerNorm --------------------
__device__ __forceinline__ void compute_y(int b, int n, int lane,
        const float* __restrict__ xg, const float cf[T_][T_],
        const float* __restrict__ x, const float* __restrict__ c1w,
        const float* __restrict__ c1b, float* y)
{
    float acc[T_];
#pragma unroll
    for (int q = 0; q < T_; ++q) acc[q] = 0.f;
#pragma unroll 1
    for (int l = 0; l < T_; ++l) {
        float xv = xg[(size_t)((b*T_ + l)*N_ + n)*64 + lane];
#pragma unroll
        for (int q = 0; q < T_; ++q) acc[q] += xv * cf[q][l];
    }
    float w0 = c1w[lane*3+0], w1 = c1w[lane*3+1], w2 = c1w[lane*3+2];
    float bb = c1b[lane];
    const float* xb0 = x + ((b*CIN + 0)*N_ + n)*T_;
    const float* xb1 = x + ((b*CIN + 1)*N_ + n)*T_;
    const float* xb2 = x + ((b*CIN + 2)*N_ + n)*T_;
#pragma unroll
    for (int q = 0; q < T_; ++q) {
        float xin = bb + w0*xb0[q] + w1*xb1[q] + w2*xb2[q];
        float v = acc[q];
        v = v > 0.f ? v : 0.01f*v;
        y[q] = v + xin;
    }
}

__global__ __launch_bounds__(256) void kE1(const float* __restrict__ xg,
        const float* __restrict__ coefs, const float* __restrict__ x,
        const float* __restrict__ c1w, const float* __restrict__ c1b,
        float* __restrict__ stats)
{
    __shared__ float cf[T_][T_];
    int b = blockIdx.y;
    for (int i = threadIdx.x; i < T_*T_; i += 256) ((float*)cf)[i] = coefs[b*T_*T_ + i];
    __syncthreads();
    int w = threadIdx.x >> 6, lane = threadIdx.x & 63;
    int n = blockIdx.x*4 + w;
    if (n >= N_) return;
    float y[T_];
    compute_y(b, n, lane, xg, cf, x, c1w, c1b, y);
    float s = 0.f, ss = 0.f;
#pragma unroll
    for (int q = 0; q < T_; ++q) { s += y[q]; ss += y[q]*y[q]; }
    s = wave_sum(s); ss = wave_sum(ss);
    if (lane == 0) { atomicAdd(&stats[2*b], s); atomicAdd(&stats[2*b + 1], ss); }
}

__global__ __launch_bounds__(256) void kE2(const float* __restrict__ xg,
        const float* __restrict__ coefs, const float* __restrict__ x,
        const float* __restrict__ c1w, const float* __restrict__ c1b,
        const float* __restrict__ stats, const float* __restrict__ lnw,
        const float* __restrict__ lnb, float* __restrict__ out)
{
    __shared__ float cf[T_][T_];
    int b = blockIdx.y;
    for (int i = threadIdx.x; i < T_*T_; i += 256) ((float*)cf)[i] = coefs[b*T_*T_ + i];
    __syncthreads();
    int w = threadIdx.x >> 6, lane = threadIdx.x & 63;
    int n = blockIdx.x*4 + w;
    if (n >= N_) return;
    float y[T_];
    compute_y(b, n, lane, xg, cf, x, c1w, c1b, y);
    float mu   = stats[2*b] * (1.f/CNT);
    float var  = stats[2*b + 1] * (1.f/CNT) - mu*mu;
    float rstd = rsqrtf(fmaxf(var, 0.f) + 1e-5f);
    int gi = (lane*N_ + n)*T_;
    float ov[T_];
#pragma unroll
    for (int q = 0; q < T_; ++q)
        ov[q] = (y[q] - mu)*rstd*lnw[gi + q] + lnb[gi + q];
    float* dst = out + ((size_t)(b*C + lane)*N_ + n)*T_;
#pragma unroll
    for (int j = 0; j < 6; ++j) {
        float4 v;
        v.x = ov[j*4+0]; v.y = ov[j*4+1]; v.z = ov[j*4+2]; v.w = ov[j*4+3];
        ((float4*)dst)[j] = v;
    }
}

extern "C" void kernel_launch(void* const* d_in, const int* in_sizes, int n_in,
                              void* d_out, int out_size, void* d_ws, size_t ws_size,
                              hipStream_t stream)
{
    const float* x   = (const float*)d_in[0];
    const float* sup = (const float*)d_in[1];
    const float* c1w = (const float*)d_in[2];
    const float* c1b = (const float*)d_in[3];
    const float* tmw = (const float*)d_in[4];
    const float* tmb = (const float*)d_in[5];
    const float* W1  = (const float*)d_in[6];
    const float* a1s = (const float*)d_in[7];
    const float* a1d = (const float*)d_in[8];
    const float* W2  = (const float*)d_in[9];
    const float* a2s = (const float*)d_in[10];
    const float* a2d = (const float*)d_in[11];
    const float* t1w = (const float*)d_in[12];
    const float* t2w = (const float*)d_in[13];
    const float* tw  = (const float*)d_in[14];
    const float* tb  = (const float*)d_in[15];
    const float* tv  = (const float*)d_in[16];
    const float* bng = (const float*)d_in[17];
    const float* bnb = (const float*)d_in[18];
    const float* lnw = (const float*)d_in[19];
    const float* lnb = (const float*)d_in[20];

    float* out = (float*)d_out;
    float* Sc  = out + OUT_ELEMS;               // final S_coef region (f32)
    float* Tc  = Sc + (size_t)S_ELEMS;          // final T_coef region (f32)

    // ALL scratch lives inside the Sc region (overwritten last by kSc).
    // d_ws is never touched.
    float* agbuf  = Sc;                          // OUT_ELEMS f32
    float* f1     = Sc + (size_t)OUT_ELEMS;      // ROWS f32
    float* f2part = f1 + ROWS;                   // 2*BZ*C*T_ f32
    float* g1     = f2part + 2*BZ*C*T_;          // BT*C f32
    float* coefs  = g1 + BT*C;                   // BZ*T_*T_ f32
    float* stats  = coefs + BZ*T_*T_;            // 32 f32

    kGAT<0><<<dim3(2, BT), 256, 0, stream>>>(x, sup, tmw, tmb, W1, a1s, a1d,
                                             t1w, t2w, agbuf, f1, f2part);
    kGAT<1><<<dim3(2, BT), 256, 0, stream>>>(x, sup, tmw, tmb, W2, a2s, a2d,
                                             t1w, t2w, agbuf, f1, f2part);
    kD0<<<BT, 256, 0, stream>>>(f1, tw, g1);
    kD<<<BZ, 256, 0, stream>>>(g1, f2part, tb, tv, bng, bnb, coefs, Tc, stats);
    kE1<<<dim3(77, BZ), 256, 0, stream>>>(agbuf, coefs, x, c1w, c1b, stats);
    kE2<<<dim3(77, BZ), 256, 0, stream>>>(agbuf, coefs, x, c1w, c1b, stats, lnw, lnb, out);
    kSc<<<dim3(2, BT), 256, 0, stream>>>(x, sup, tmw, tmb, W1, a1s, a1d, Sc);
}

// Round 10
// 1191.062 us; speedup vs baseline: 1.2594x; 1.2594x over previous
//
#include <hip/hip_runtime.h>

typedef unsigned short u16;
typedef unsigned int u32;
typedef __attribute__((ext_vector_type(8))) short bf16x8;
typedef __attribute__((ext_vector_type(4))) float f32x4;

#define BZ 16
#define CIN 3
#define C 64
#define N_ 307
#define T_ 24
#define BT (BZ*T_)          // 384
#define ROWS (BT*N_)        // 117888
#define CNT (C*N_*T_)       // 471552

#define OUT_ELEMS 7544832
#define S_ELEMS   36191616

#define HSTRIDE 344         // u16 stride of sHT rows: 688 B = 43*16 (16B-aligned b128)

__device__ __forceinline__ float bf(const u16* p, int i) {
    union { unsigned u; float f; } x; x.u = ((unsigned)p[i]) << 16; return x.f;
}
__device__ __forceinline__ u16 f2b(float v) {
    union { float f; unsigned u; } x; x.f = v;
    unsigned u = x.u;
    unsigned rb = (u >> 16) & 1u;
    u += 0x7fffu + rb;
    return (u16)(u >> 16);
}
__device__ __forceinline__ float wave_sum(float v) {
#pragma unroll
    for (int m = 32; m > 0; m >>= 1) v += __shfl_xor(v, m);
    return v;
}
__device__ __forceinline__ float rdlane(float v, int l) {
    return __int_as_float(__builtin_amdgcn_readlane(__float_as_int(v), l));
}

// temporal conv (lrelu 0.01) for 4 rows owned by this wave; lane = out channel
__device__ __forceinline__ void tconv4(const float* __restrict__ x,
        const float* __restrict__ tmw, const float* __restrict__ tmb,
        int b, int t, int n0, int lane, float xt4[4])
{
#pragma unroll
    for (int r = 0; r < 4; ++r) {
        int n = n0 + r;
        float acc = tmb[lane];
        if (n < N_) {
#pragma unroll
            for (int ci = 0; ci < CIN; ++ci) {
                const float* xp = x + ((b*CIN + ci)*N_ + n)*T_;
                float wa = tmw[(lane*CIN + ci)*3 + 0];
                float wb = tmw[(lane*CIN + ci)*3 + 1];
                float wc = tmw[(lane*CIN + ci)*3 + 2];
                if (t > 0)      acc += wa * xp[t - 1];
                acc += wb * xp[t];
                if (t < T_ - 1) acc += wc * xp[t + 1];
            }
        }
        xt4[r] = acc > 0.f ? acc : 0.01f * acc;
    }
}

// GAT weight for kSc (precise expf path, unchanged from round 9)
__device__ __forceinline__ float gatw(const float* __restrict__ sup,
        int n, int m, bool mv, float hsv, float hdv)
{
    float wv = 0.f;
    if (mv && n < N_) {
        bool adj = sup[n*N_ + m] > 0.f;
        float ea = hsv + hdv; ea = ea > 0.f ? ea : 0.3f*ea;
        wv = adj ? expf(ea) : 0.f;
    }
    return wv;
}

// ===== kGAT<G>: temporal conv + single GAT; att@h via bf16 MFMA ==============
// Grid BT, 256 threads = 4 waves. Wave w owns M-tiles mt = w + 4*i, i<5
// (16 rows each, 320 padded rows). A-frags (w weights) generated in registers
// (one exp pass; row-sums fused). B-frags = h, staged transposed in LDS
// sHT[c][m] (bf16, stride 344 u16 -> aligned ds_read_b128).
// Round-10 change: round 7-9 showed the att@h VALU matmul is the floor
// (9.7 GMAC on VALU >= 250 us); MFMA does it at bf16 rate.
template<int G>
__global__ __launch_bounds__(256) void kGAT(
        const float* __restrict__ x, const float* __restrict__ sup,
        const float* __restrict__ tmw, const float* __restrict__ tmb,
        const float* __restrict__ W, const float* __restrict__ asp,
        const float* __restrict__ adp,
        const float* __restrict__ t1w, const float* __restrict__ t2w,
        float* __restrict__ agbuf, float* __restrict__ f1,
        float* __restrict__ f2)
{
    __shared__ u16 sHT[64*HSTRIDE];  // 44 KB, h transposed [c][m] bf16
    __shared__ float sHs[320];
    __shared__ float sHd[320];
    __shared__ float sF2[4*64];

    int bt = blockIdx.x;
    int b = bt / T_, t = bt - b * T_;
    int tid = threadIdx.x;
    int w = tid >> 6, lane = tid & 63;
    int l15 = lane & 15, quad = lane >> 4;

    // pad init: sHT m=307..343 zero (avoid 0*NaN in MFMA); hs/hd pad -700 -> w=0
    for (int idx = tid; idx < 64*37; idx += 256) {
        int c = idx / 37, o = idx - c*37;
        sHT[c*HSTRIDE + 307 + o] = 0;
    }
    if (tid < 13) { sHs[307+tid] = -700.f; sHd[307+tid] = -700.f; }

    float wreg[64];
#pragma unroll
    for (int c = 0; c < 64; ++c) wreg[c] = W[c*64 + lane];
    float asv = asp[lane], adv = adp[lane];

    // ---- phase 1: tconv + h = xt@W (readlane) + hs/hd; store h^T bf16 ----
#pragma unroll 1
    for (int g = 0; g < 20; ++g) {
        int n0 = g*16 + w*4;
        float xt4[4];
        tconv4(x, tmw, tmb, b, t, n0, lane, xt4);
        float h[4] = {0,0,0,0};
#pragma unroll
        for (int c = 0; c < 64; ++c) {
#pragma unroll
            for (int r = 0; r < 4; ++r) h[r] += rdlane(xt4[r], c) * wreg[c];
        }
#pragma unroll
        for (int r = 0; r < 4; ++r) {
            int n = n0 + r;
            float v1 = wave_sum(h[r] * asv);
            float v2 = wave_sum(h[r] * adv);
            if (n < N_) {
                sHT[lane*HSTRIDE + n] = f2b(h[r]);
                if (lane == 0) { sHs[n] = v1; sHd[n] = v2; }
            }
        }
    }
    __syncthreads();

    // ---- phase 2: A-frag generation + MFMA att@h + epilogue ----
    float t1all[4];
    if (G == 1) {
#pragma unroll
        for (int nt = 0; nt < 4; ++nt) t1all[nt] = t1w[nt*16 + l15];
    }
    float q[4] = {0,0,0,0};

#pragma unroll 1
    for (int i = 0; i < 5; ++i) {
        int mt = w + 4*i;
        int n = mt*16 + l15;                 // A row owned by this lane
        float hsv = sHs[n];
        int nclamp = (n < N_) ? n : 0;
        const float* srow = sup + nclamp*N_;
        float asum = 0.f;
        bf16x8 af[10];
#pragma unroll
        for (int ks = 0; ks < 10; ++ks) {
            int m0 = ks*32 + quad*8;
            bf16x8 a;
#pragma unroll
            for (int j = 0; j < 8; ++j) {
                int m = m0 + j;
                float hdv = sHd[m];
                float e = hsv + hdv; e = e > 0.f ? e : 0.3f*e;
                float ww = 0.f;
                if (m < N_ && srow[m] > 0.f) ww = __expf(e);
                asum += ww;
                a[j] = (short)f2b(ww);
            }
            af[ks] = a;
        }
        // full row sum (lane's k-slice + across quads); every lane then holds
        // the sum for row = its l15
        asum += __shfl_xor(asum, 16);
        asum += __shfl_xor(asum, 32);
        float invv = (asum > 0.f) ? 1.f/asum : 0.f;

        float p[4] = {0,0,0,0};
#pragma unroll 1
        for (int nt = 0; nt < 4; ++nt) {
            f32x4 acc = {0.f, 0.f, 0.f, 0.f};
            const u16* bbase = sHT + (nt*16 + l15)*HSTRIDE;
#pragma unroll
            for (int ks = 0; ks < 10; ++ks) {
                bf16x8 bfrag = *(const bf16x8*)(bbase + ks*32 + quad*8);
                acc = __builtin_amdgcn_mfma_f32_16x16x32_bf16(af[ks], bfrag, acc, 0, 0, 0);
            }
            int c = nt*16 + l15;
#pragma unroll
            for (int reg = 0; reg < 4; ++reg) {
                int n2 = mt*16 + quad*4 + reg;       // C-layout row
                float inv2 = __shfl(invv, quad*4 + reg);
                float a = acc[reg] * inv2;
                size_t idx = (size_t)(bt*N_ + n2)*64 + c;
                if (G == 0) {
                    if (n2 < N_) agbuf[idx] = a;
                } else {
                    float a1 = (n2 < N_) ? agbuf[idx] : 0.f;
                    float gt = 1.f / (1.f + __expf(-a));
                    float fv = a1 > 0.f ? a1 : 0.01f*a1;
                    float xv = gt * fv;
                    if (n2 < N_) agbuf[idx] = xv; else xv = 0.f;
                    p[reg] += xv * t1all[nt];
                    float t2v = (n2 < N_) ? t2w[n2] : 0.f;
                    q[nt] += xv * t2v;
                }
            }
        }
        if (G == 1) {   // f1: reduce over c (l15 group; nt already in-lane)
#pragma unroll
            for (int reg = 0; reg < 4; ++reg) {
                float s = p[reg];
                s += __shfl_xor(s, 1); s += __shfl_xor(s, 2);
                s += __shfl_xor(s, 4); s += __shfl_xor(s, 8);
                int n2 = mt*16 + quad*4 + reg;
                if (l15 == 0 && n2 < N_) f1[bt*N_ + n2] = s;
            }
        }
    }
    if (G == 1) {       // f2: reduce over rows (quads), then over waves
#pragma unroll
        for (int nt = 0; nt < 4; ++nt) {
            float s = q[nt];
            s += __shfl_xor(s, 16); s += __shfl_xor(s, 32);
            if (quad == 0) sF2[w*64 + nt*16 + l15] = s;
        }
        __syncthreads();
        if (tid < 64) {
            float s = sF2[tid] + sF2[64+tid] + sF2[128+tid] + sF2[192+tid];
            f2[(b*C + tid)*T_ + t] = s;
        }
    }
}

// ===== kSc: recompute GAT1 softmax and write S_coef (runs LAST) ==============
__global__ __launch_bounds__(256) void kSc(
        const float* __restrict__ x, const float* __restrict__ sup,
        const float* __restrict__ tmw, const float* __restrict__ tmb,
        const float* __restrict__ W, const float* __restrict__ asp,
        const float* __restrict__ adp, float* __restrict__ Sc)
{
    __shared__ float sHs[320];
    __shared__ float sHd[320];

    int half = blockIdx.x;
    int bt = blockIdx.y;
    int b = bt / T_, t = bt - b * T_;
    int tid = threadIdx.x;
    int w = tid >> 6, lane = tid & 63;

    float wreg[64];
#pragma unroll
    for (int c = 0; c < 64; ++c) wreg[c] = W[c*64 + lane];

    float asv = asp[lane], adv = adp[lane];

#pragma unroll 1
    for (int g = 0; g < 20; ++g) {
        int n0 = g * 16 + w * 4;
        float xt4[4];
        tconv4(x, tmw, tmb, b, t, n0, lane, xt4);
        float h[4] = {0,0,0,0};
#pragma unroll
        for (int c = 0; c < 64; ++c) {
#pragma unroll
            for (int r = 0; r < 4; ++r) h[r] += rdlane(xt4[r], c) * wreg[c];
        }
#pragma unroll
        for (int r = 0; r < 4; ++r) {
            int n = n0 + r;
            float v1 = wave_sum(h[r] * asv);
            float v2 = wave_sum(h[r] * adv);
            if (n < N_ && lane == 0) { sHs[n] = v1; sHd[n] = v2; }
        }
    }
    __syncthreads();

#pragma unroll 1
    for (int g = 0; g < 10; ++g) {
        int n0 = half * 160 + g * 16 + w * 4;
        float hsv[4], sm[4], inv[4];
#pragma unroll
        for (int r = 0; r < 4; ++r) {
            int n = n0 + r;
            hsv[r] = (n < N_) ? sHs[n] : 0.f;
            sm[r] = 0.f;
        }
#pragma unroll 1
        for (int c5 = 0; c5 < 5; ++c5) {
            int m = c5*64 + lane;
            bool mv = m < N_;
            float hdv = mv ? sHd[m] : 0.f;
#pragma unroll
            for (int r = 0; r < 4; ++r)
                sm[r] += gatw(sup, n0 + r, m, mv, hsv[r], hdv);
        }
#pragma unroll
        for (int r = 0; r < 4; ++r) {
            float s = wave_sum(sm[r]);
            inv[r] = (s > 0.f) ? 1.f / s : 0.f;
        }
#pragma unroll 1
        for (int c5 = 0; c5 < 5; ++c5) {
            int m = c5*64 + lane;
            bool mv = m < N_;
            float hdv = mv ? sHd[m] : 0.f;
#pragma unroll
            for (int r = 0; r < 4; ++r) {
                int n = n0 + r;
                if (mv && n < N_)
                    Sc[(size_t)(bt*N_ + n)*N_ + m] =
                        gatw(sup, n, m, mv, hsv[r], hdv) * inv[r];
            }
        }
    }
}

// ---------------- kD0: g1[bt][c] = sum_n f1[bt][n] * tw[n][c] ----------------
__global__ __launch_bounds__(256) void kD0(const float* __restrict__ f1,
        const float* __restrict__ tw, float* __restrict__ g1)
{
    __shared__ float part[4][64];
    int bt = blockIdx.x;
    int w = threadIdx.x >> 6, lane = threadIdx.x & 63;
    float acc = 0.f;
    for (int n = w*77; n < (w+1)*77 && n < N_; ++n)
        acc += f1[bt*N_ + n] * tw[n*64 + lane];
    part[w][lane] = acc;
    __syncthreads();
    if (threadIdx.x < 64) {
        float s = part[0][threadIdx.x] + part[1][threadIdx.x]
                + part[2][threadIdx.x] + part[3][threadIdx.x];
        g1[bt*64 + threadIdx.x] = s;
    }
}

// ---------------- kD: temporal attention TATT_1 ------------------------------
__global__ __launch_bounds__(256) void kD(const float* __restrict__ g1,
        const float* __restrict__ f2, const float* __restrict__ tb,
        const float* __restrict__ tv,
        const float* __restrict__ bng, const float* __restrict__ bnb,
        float* __restrict__ coefs, float* __restrict__ Tc,
        float* __restrict__ stats)
{
    __shared__ float g1s[T_][C];
    __shared__ float f2s[C][T_];
    __shared__ float lg[T_][T_];
    __shared__ float l2[T_][T_];
    int b = blockIdx.x, tid = threadIdx.x;
    if (tid == 0) { stats[2*b] = 0.f; stats[2*b + 1] = 0.f; }
    for (int idx = tid; idx < T_*C; idx += 256) {
        int t = idx / C, c = idx - t*C;
        g1s[t][c] = g1[(b*T_ + t)*C + c];
        int c2 = idx / T_, t2 = idx - c2*T_;
        f2s[c2][t2] = f2[(b*C + c2)*T_ + t2];
    }
    __syncthreads();
    for (int idx = tid; idx < T_*T_; idx += 256) {
        int t = idx / T_, q = idx - t*T_;
        float s = 0.f;
#pragma unroll
        for (int c = 0; c < C; ++c) s += g1s[t][c] * f2s[c][q];
        s += tb[t*T_ + q];
        lg[t][q] = 1.f / (1.f + expf(-s));
    }
    __syncthreads();
    const float bnscale = 0.99999500003749972f;  // 1/sqrt(1+1e-5)
    for (int idx = tid; idx < T_*T_; idx += 256) {
        int p = idx / T_, q = idx - p*T_;
        float s = 0.f;
#pragma unroll
        for (int t = 0; t < T_; ++t) s += tv[p*T_ + t] * lg[t][q];
        s = s * bnscale * bng[q] + bnb[q];
        if (q > p) s += -1e13f;   // causal mask
        l2[p][q] = s;
    }
    __syncthreads();
    if (tid < T_) {
        int p = tid;
        float mx = -3e38f;
#pragma unroll
        for (int q = 0; q < T_; ++q) mx = fmaxf(mx, l2[p][q]);
        float e[T_]; float sum = 0.f;
#pragma unroll
        for (int q = 0; q < T_; ++q) { e[q] = expf(l2[p][q] - mx); sum += e[q]; }
        float inv = 1.f / sum;
#pragma unroll
        for (int q = 0; q < T_; ++q) {
            float v = e[q] * inv;
            coefs[(b*T_ + p)*T_ + q] = v;
            Tc[(b*T_ + q)*T_ + p] = v;
        }
    }
}

// ---------------- kE: temporal mix + residual + LayerNorm --------------------
__device__ __forceinline__ void compute_y(int b, int n, int lane,
        const float* __restrict__ xg, const float cf[T_][T_],
        const float* __restrict__ x, const float* __restrict__ c1w,
        const float* __restrict__ c1b, float* y)
{
    float acc[T_];
#pragma unroll
    for (int q = 0; q < T_; ++q) acc[q] = 0.f;
#pragma unroll 1
    for (int l = 0; l < T_; ++l) {
        float xv = xg[(size_t)((b*T_ + l)*N_ + n)*64 + lane];
#pragma unroll
        for (int q = 0; q < T_; ++q) acc[q] += xv * cf[q][l];
    }
    float w0 = c1w[lane*3+0], w1 = c1w[lane*3+1], w2 = c1w[lane*3+2];
    float bb = c1b[lane];
    const float* xb0 = x + ((b*CIN + 0)*N_ + n)*T_;
    const float* xb1 = x + ((b*CIN + 1)*N_ + n)*T_;
    const float* xb2 = x + ((b*CIN + 2)*N_ + n)*T_;
#pragma unroll
    for (int q = 0; q < T_; ++q) {
        float xin = bb + w0*xb0[q] + w1*xb1[q] + w2*xb2[q];
        float v = acc[q];
        v = v > 0.f ? v : 0.01f*v;
        y[q] = v + xin;
    }
}

__global__ __launch_bounds__(256) void kE1(const float* __restrict__ xg,
        const float* __restrict__ coefs, const float* __restrict__ x,
        const float* __restrict__ c1w, const float* __restrict__ c1b,
        float* __restrict__ stats)
{
    __shared__ float cf[T_][T_];
    int b = blockIdx.y;
    for (int i = threadIdx.x; i < T_*T_; i += 256) ((float*)cf)[i] = coefs[b*T_*T_ + i];
    __syncthreads();
    int w = threadIdx.x >> 6, lane = threadIdx.x & 63;
    int n = blockIdx.x*4 + w;
    if (n >= N_) return;
    float y[T_];
    compute_y(b, n, lane, xg, cf, x, c1w, c1b, y);
    float s = 0.f, ss = 0.f;
#pragma unroll
    for (int q = 0; q < T_; ++q) { s += y[q]; ss += y[q]*y[q]; }
    s = wave_sum(s); ss = wave_sum(ss);
    if (lane == 0) { atomicAdd(&stats[2*b], s); atomicAdd(&stats[2*b + 1], ss); }
}

__global__ __launch_bounds__(256) void kE2(const float* __restrict__ xg,
        const float* __restrict__ coefs, const float* __restrict__ x,
        const float* __restrict__ c1w, const float* __restrict__ c1b,
        const float* __restrict__ stats, const float* __restrict__ lnw,
        const float* __restrict__ lnb, float* __restrict__ out)
{
    __shared__ float cf[T_][T_];
    int b = blockIdx.y;
    for (int i = threadIdx.x; i < T_*T_; i += 256) ((float*)cf)[i] = coefs[b*T_*T_ + i];
    __syncthreads();
    int w = threadIdx.x >> 6, lane = threadIdx.x & 63;
    int n = blockIdx.x*4 + w;
    if (n >= N_) return;
    float y[T_];
    compute_y(b, n, lane, xg, cf, x, c1w, c1b, y);
    float mu   = stats[2*b] * (1.f/CNT);
    float var  = stats[2*b + 1] * (1.f/CNT) - mu*mu;
    float rstd = rsqrtf(fmaxf(var, 0.f) + 1e-5f);
    int gi = (lane*N_ + n)*T_;
    float ov[T_];
#pragma unroll
    for (int q = 0; q < T_; ++q)
        ov[q] = (y[q] - mu)*rstd*lnw[gi + q] + lnb[gi + q];
    float* dst = out + ((size_t)(b*C + lane)*N_ + n)*T_;
#pragma unroll
    for (int j = 0; j < 6; ++j) {
        float4 v;
        v.x = ov[j*4+0]; v.y = ov[j*4+1]; v.z = ov[j*4+2]; v.w = ov[j*4+3];
        ((float4*)dst)[j] = v;
    }
}

extern "C" void kernel_launch(void* const* d_in, const int* in_sizes, int n_in,
                              void* d_out, int out_size, void* d_ws, size_t ws_size,
                              hipStream_t stream)
{
    const float* x   = (const float*)d_in[0];
    const float* sup = (const float*)d_in[1];
    const float* c1w = (const float*)d_in[2];
    const float* c1b = (const float*)d_in[3];
    const float* tmw = (const float*)d_in[4];
    const float* tmb = (const float*)d_in[5];
    const float* W1  = (const float*)d_in[6];
    const float* a1s = (const float*)d_in[7];
    const float* a1d = (const float*)d_in[8];
    const float* W2  = (const float*)d_in[9];
    const float* a2s = (const float*)d_in[10];
    const float* a2d = (const float*)d_in[11];
    const float* t1w = (const float*)d_in[12];
    const float* t2w = (const float*)d_in[13];
    const float* tw  = (const float*)d_in[14];
    const float* tb  = (const float*)d_in[15];
    const float* tv  = (const float*)d_in[16];
    const float* bng = (const float*)d_in[17];
    const float* bnb = (const float*)d_in[18];
    const float* lnw = (const float*)d_in[19];
    const float* lnb = (const float*)d_in[20];

    float* out = (float*)d_out;
    float* Sc  = out + OUT_ELEMS;               // final S_coef region (f32)
    float* Tc  = Sc + (size_t)S_ELEMS;          // final T_coef region (f32)

    // ALL scratch lives inside the Sc region (overwritten last by kSc).
    // d_ws is never touched.
    float* agbuf = Sc;                          // OUT_ELEMS f32
    float* f1    = Sc + (size_t)OUT_ELEMS;      // ROWS f32
    float* f2    = f1 + ROWS;                   // BZ*C*T_ f32
    float* g1    = f2 + BZ*C*T_;                // BT*C f32
    float* coefs = g1 + BT*C;                   // BZ*T_*T_ f32
    float* stats = coefs + BZ*T_*T_;            // 32 f32

    kGAT<0><<<BT, 256, 0, stream>>>(x, sup, tmw, tmb, W1, a1s, a1d,
                                    t1w, t2w, agbuf, f1, f2);
    kGAT<1><<<BT, 256, 0, stream>>>(x, sup, tmw, tmb, W2, a2s, a2d,
                                    t1w, t2w, agbuf, f1, f2);
    kD0<<<BT, 256, 0, stream>>>(f1, tw, g1);
    kD<<<BZ, 256, 0, stream>>>(g1, f2, tb, tv, bng, bnb, coefs, Tc, stats);
    kE1<<<dim3(77, BZ), 256, 0, stream>>>(agbuf, coefs, x, c1w, c1b, stats);
    kE2<<<dim3(77, BZ), 256, 0, stream>>>(agbuf, coefs, x, c1w, c1b, stats, lnw, lnb, out);
    kSc<<<dim3(2, BT), 256, 0, stream>>>(x, sup, tmw, tmb, W1, a1s, a1d, Sc);
}